// Round 15
// baseline (135.014 us; speedup 1.0000x reference)
//
#include <hip/hip_runtime.h>
#include <math.h>

// Problem constants (fixed by the reference):
#define BB 32     // batch
#define NN 128    // nodes
#define CC 16     // in_ch
#define OO 32     // out_ch
#define II 32     // in_dim
#define JJ 32     // out_dim
#define MM (NN*CC)  // 2048 input capsules per (b, out_ch)
static constexpr float EPS_ = 1e-11f;

// ROUND-15: single-o blocks for 2-blocks/CU co-residency.
// Round-14 showed the 2-round 1-block/CU structure leaves prologue+stall
// time unhidden (37% occupancy, 60% stall, zero in-loop global traffic).
// Split (b,o-pair) -> 2x (b,o): 1024 blocks, Ws 64 KB (unpadded), total
// LDS 78.3 KB -> TWO blocks/CU; block 2's W-stage/x-load/barrier drain
// overlaps block 1's compute. Per-thread work & registers halve (one o).
// Bank strategy without the +1 pad:
//   A:  lanes on j, rows stride 32 -> consecutive banks; half-waves hit
//       the same bank at different addresses = 2-way = free (m136).
//   Wv: diagonal j = jh*16 + ((jj+i)&15) -> 32 banks x 2 lanes = free.
//   U:  wv read as two same-address broadcasts (wvp halves).
// cxs/wvp time-share one 4 KB buffer: all wvp reads precede BAR3; all
// next-iter cxs writes follow it (no overlap race).
// Spill tripwire: WRITE_SIZE should stay ~8-16 MB (16 B/thread).

// ---- one-time transpose: xT[b][c][i][n] = x[b][n][c][i] ----
__global__ __launch_bounds__(1024) void k_transpose(
    const float* __restrict__ x, float* __restrict__ xT) {
  int b = blockIdx.x >> 4, c = blockIdx.x & 15;
  __shared__ __align__(16) float xsT[II][NN + 4];   // +4: f4-aligned padded rows
  int tid = threadIdx.x;
  {
    int n = tid >> 3, i4 = (tid & 7) * 4;
    float4 v = *(const float4*)(x + (((size_t)(b * NN + n)) * CC + c) * II + i4);
    xsT[i4 + 0][n] = v.x; xsT[i4 + 1][n] = v.y;
    xsT[i4 + 2][n] = v.z; xsT[i4 + 3][n] = v.w;
  }
  __syncthreads();
  {
    int i = tid >> 5, n4 = tid & 31;
    float4 v = *(const float4*)(&xsT[i][n4 * 4]);   // row stride 528 B, 16B-aligned
    ((float4*)(xT + ((size_t)(b * CC + c)) * II * NN))[tid] = v;
  }
}

// 16-slot reduce-scatter across lane bits 1..4 (n4 bits); returns the
// fully-reduced value for slot qf = this lane's bit-pattern.
__device__ __forceinline__ float rs16(float p[16], int l) {
  bool u2 = (l >> 1) & 1, u4 = (l >> 2) & 1, u8 = (l >> 3) & 1, u16 = (l >> 4) & 1;
  #pragma unroll
  for (int k = 0; k < 8; ++k) {
    float s0 = u2 ? p[k] : p[k + 8];
    float r0 = __shfl_xor(s0, 2);
    p[k] = (u2 ? p[k + 8] : p[k]) + r0;
  }
  #pragma unroll
  for (int k = 0; k < 4; ++k) {
    float s0 = u4 ? p[k] : p[k + 4];
    float r0 = __shfl_xor(s0, 4);
    p[k] = (u4 ? p[k + 4] : p[k]) + r0;
  }
  #pragma unroll
  for (int k = 0; k < 2; ++k) {
    float s0 = u8 ? p[k] : p[k + 2];
    float r0 = __shfl_xor(s0, 8);
    p[k] = (u8 ? p[k + 2] : p[k]) + r0;
  }
  {
    float s0 = u16 ? p[0] : p[1];
    float r0 = __shfl_xor(s0, 16);
    p[0] = (u16 ? p[1] : p[0]) + r0;
  }
  p[0] += __shfl_xor(p[0], 32);          // allreduce the last n4 bit
  return p[0];
}

// ---- the whole routing loop. Block per (b, o). 1024 threads. ----
__global__ __launch_bounds__(1024) void k_route(
    const float* __restrict__ xT, const float* __restrict__ W,
    float* __restrict__ out) {
  int bid = blockIdx.x;
  int b = bid & 31, o = bid >> 5;             // same-b blocks share an XCD
  int tid = threadIdx.x;

  __shared__ float Ws[CC * II * JJ];                // 64 KB: W[:,o,:,:], unpadded
  __shared__ __align__(16) float bijL[CC][NN];      // 8 KB routing logits
  __shared__ float cwbuf[CC * II * 2];              // 4 KB: cxs / wvp (time-shared)
  __shared__ float partA[CC][JJ];                   // 2 KB
  __shared__ float vs[JJ];
  __shared__ float redM[CC], redE[CC];
  // total ~78.3 KB -> 2 blocks/CU

  // ---- stage Ws (once; W iteration-invariant). 4096 f4 / 1024 threads ----
  {
    #pragma unroll
    for (int k = 0; k < 4; ++k) {
      int f4i = tid + k * 1024;          // (c, i, jq): c = f4i>>8
      int cc = f4i >> 8, rem = f4i & 255;
      float4 v = *(const float4*)(W + (((size_t)(cc * OO + o)) * II) * JJ + rem * 4);
      *(float4*)(&Ws[cc * II * JJ + rem * 4]) = v;
    }
  }

  // x -> registers (once): thread (c, n4, s) owns i=s*16..s*16+15, n=n4*4..+3
  int l = tid & 63;
  int c = tid >> 6, n4 = l >> 1, s = l & 1;
  const float4* xTb = (const float4*)(xT + (size_t)b * CC * II * NN);
  const float4* xp  = xTb + c * (II * NN / 4) + (s * 16) * (NN / 4) + n4;
  float4 xv[16];
  #pragma unroll
  for (int q = 0; q < 16; ++q) xv[q] = xp[q * (NN / 4)];  // 512B runs, coalesced

  {  // init: bijL = 0 (2048 f4... 2048 floats = 512 f4; 1024 thr: gate)
    if (tid < 512) ((float4*)bijL)[tid] = make_float4(0.f, 0.f, 0.f, 0.f);
  }
  // softmax stats in registers; iter-0 uniform: mo=0, rin=1/MM (exact pow2)
  float mo = 0.f, rin = 1.0f / (float)MM;
  __syncthreads();

  for (int it = 0; it < 3; ++it) {
    // --- C: cxs[c][i] = sum_n coef(c,n)*x(c,n,i); coef from bijL+regs ---
    {
      int qf = ((l >> 1) & 1) * 8 + ((l >> 2) & 1) * 4
             + ((l >> 3) & 1) * 2 + ((l >> 4) & 1);
      float4 bb = *(const float4*)(&bijL[c][n4 * 4]);
      float cfx = __expf(bb.x - mo) * rin, cfy = __expf(bb.y - mo) * rin;
      float cfz = __expf(bb.z - mo) * rin, cfw = __expf(bb.w - mo) * rin;
      float p[16];
      #pragma unroll
      for (int q = 0; q < 16; ++q)
        p[q] = xv[q].x*cfx + xv[q].y*cfy + xv[q].z*cfz + xv[q].w*cfw;
      float r = rs16(p, l);
      if ((l & 32) == 0) cwbuf[c * II + s * 16 + qf] = r;
    }
    // NO barrier: A below is wave-aligned (wave c consumes its own cxs)

    // --- A: partA[c][j] = sum_i cxs[c][i]*Ws[c,i,j]; i split across
    //     half-waves, combined via shfl_xor(32)  (pure LDS) ---
    {
      int cA = tid >> 6, j = l & 31, ih = l >> 5;
      const float* wsp = &Ws[(cA * II + ih * 16) * JJ + j];
      const float* cxp = &cwbuf[cA * II + ih * 16];
      float acc = 0.f;
      #pragma unroll
      for (int q = 0; q < 16; ++q)
        acc += cxp[q] * wsp[q * JJ];     // cxp 2-addr broadcast; banks = j
      acc += __shfl_xor(acc, 32);        // combine i-halves
      if (ih == 0) partA[cA][j] = acc;
    }
    __syncthreads();                     // BAR1: squash needs all c

    // --- A-reduce + squash (final iter writes output) ---
    if (tid < 32) {
      int j = tid;
      float sA = 0.f;
      #pragma unroll
      for (int cR = 0; cR < CC; ++cR) sA += partA[cR][j];
      float msq = sA * sA;
      #pragma unroll
      for (int off = 16; off > 0; off >>= 1) msq += __shfl_xor(msq, off);
      float mag = sqrtf(msq) + EPS_;
      float a   = msq / (1.0f + msq);
      float vvq = a * sA / mag;
      if (it == 2) {
        int row = b * OO + o;
        out[(size_t)row * JJ + j] = vvq;               // v_j: [B,1,O,J] flat
        if (j == 0) out[BB * OO * JJ + row] = a;       // a_j: [B,1,O,1] flat
      } else {
        vs[j] = vvq;
      }
    }
    if (it == 2) break;                   // uniform exit
    __syncthreads();                      // BAR2: Wv needs vs

    // --- Wv: wvp[c][i][jh] = sum over this j-half (diagonal order) ---
    {
      int cW = tid >> 6, i = l & 31, jh = l >> 5;
      const float* wsr = &Ws[(cW * II + i) * JJ];
      float acc = 0.f;
      #pragma unroll
      for (int jj = 0; jj < 16; ++jj) {
        int j = jh * 16 + ((jj + i) & 15);   // 32 banks x 2 lanes: free
        acc += wsr[j] * vs[j];
      }
      cwbuf[(cW * II + i) * 2 + jh] = acc;   // buffer now holds wvp
    }
    // NO barrier: U below is wave-aligned (wave c consumes its own wvp)

    // --- U: bijL += x.wv (x regs; wv = 2 broadcasts); 1-barrier stats ---
    {
      float4 ac = make_float4(0.f, 0.f, 0.f, 0.f);
      #pragma unroll
      for (int q = 0; q < 16; ++q) {
        int i = s * 16 + q;
        float w = cwbuf[(c * II + i) * 2] + cwbuf[(c * II + i) * 2 + 1];
        ac.x += xv[q].x * w; ac.y += xv[q].y * w;
        ac.z += xv[q].z * w; ac.w += xv[q].w * w;
      }
      // combine i-halves across the s-pair (both lanes end with full sum)
      ac.x += __shfl_xor(ac.x, 1); ac.y += __shfl_xor(ac.y, 1);
      ac.z += __shfl_xor(ac.z, 1); ac.w += __shfl_xor(ac.w, 1);
      float4 bb = *(const float4*)(&bijL[c][n4 * 4]);
      float4 r;
      r.x = ac.x + bb.x; r.y = ac.y + bb.y;
      r.z = ac.z + bb.z; r.w = ac.w + bb.w;
      if (s == 0) *(float4*)(&bijL[c][n4 * 4]) = r;

      // wave-local max + sum of exp(r - m_w); parity-preserving offsets
      // (values duplicated across s-pairs -> offsets 2..32 avoid double count)
      float m4 = fmaxf(fmaxf(r.x, r.y), fmaxf(r.z, r.w));
      #pragma unroll
      for (int off = 2; off <= 32; off <<= 1) m4 = fmaxf(m4, __shfl_xor(m4, off));
      float e = __expf(r.x - m4) + __expf(r.y - m4)
              + __expf(r.z - m4) + __expf(r.w - m4);
      #pragma unroll
      for (int off = 2; off <= 32; off <<= 1) e += __shfl_xor(e, off);
      int wave = tid >> 6;
      if ((tid & 63) == 0) { redM[wave] = m4; redE[wave] = e; }
      __syncthreads();                    // BAR3: the only stats barrier
      float m = redM[0];
      #pragma unroll
      for (int w2 = 1; w2 < CC; ++w2) m = fmaxf(m, redM[w2]);
      float ss = 0.f;
      #pragma unroll
      for (int w2 = 0; w2 < CC; ++w2)
        ss += redE[w2] * __expf(redM[w2] - m);
      mo = m; rin = 1.0f / ss;
      // no loop-end barrier: next C reads bijL written by THIS wave; cwbuf
      // (cxs) writes happen after BAR3 which all wvp reads precede.
    }
  }
}

extern "C" void kernel_launch(void* const* d_in, const int* in_sizes, int n_in,
                              void* d_out, int out_size, void* d_ws, size_t ws_size,
                              hipStream_t stream) {
  const float* x = (const float*)d_in[0];   // [B,N,C,I]
  const float* W = (const float*)d_in[1];   // [C,O,I,J]
  (void)in_sizes; (void)n_in;               // d_in[2] = number_of_nodes (fixed 128)
  float* out = (float*)d_out; (void)out_size;

  float* xT = (float*)d_ws;                 // 2,097,152 floats (8 MB), i-major
  (void)ws_size;

  k_transpose<<<BB * CC, 1024, 0, stream>>>(x, xT);
  k_route<<<BB * OO, 1024, 0, stream>>>(xT, W, out);
}

// Round 16
// 106.230 us; speedup vs baseline: 1.2710x; 1.2710x over previous
//
#include <hip/hip_runtime.h>
#include <math.h>

// Problem constants (fixed by the reference):
#define BB 32     // batch
#define NN 128    // nodes
#define CC 16     // in_ch
#define OO 32     // out_ch
#define II 32     // in_dim
#define JJ 32     // out_dim
#define MM (NN*CC)  // 2048 input capsules per (b, out_ch)
#define WP (JJ+1)   // padded Ws row: 33 floats -> conflict-free for BOTH
                    // A (lanes on j, stride-WP rows) and Wv (lanes on i,
                    // bank (i*33+j)%32 = (i+j)%32, distinct per lane)
static constexpr float EPS_ = 1e-11f;

// FINAL STATE = ROUND-11 (best verified: 107.4 us total, k_route 47.2 us).
// One block owns a (b, o-pair) end-to-end; zero global memory operations
// inside the routing loop:
//   * x register-resident: xv[16] f4/thread via xT (loaded once).
//   * W LDS-resident: Ws = the block's 2-o slice, staged once (132 KB,
//     WP=33 padded rows -> conflict-free for A and Wv patterns).
//   * coef recomputed from bijL + smx/srin each iter (8 exp/thread);
//     iter-0 uniform softmax falls out of smx=0, srin=1/MM exactly.
// LDS ~160.3 KB -> 1 block/CU. VGPR wall: allocator gives 1024-thread
// blocks exactly 64 VGPRs (rounds 3/4/8/9/10 all failed to move it);
// this structure fits with ~16 B/thread residual spill (~8 MB WRITE).
// Post-round-11 attempts all regressed or were neutral:
//   r12 raw-x single-kernel: 400 MB spill (k_route 127 us)
//   r13 U f4-reads:           55 MB spill (65 us)
//   r14 barrier surgery 7->3: neutral (49 us)
//   r15 single-o 2-blk/CU:    40 MB spill + 1.1M bank conflicts (80 us)

// ---- one-time transpose: xT[b][c][i][n] = x[b][n][c][i] ----
__global__ __launch_bounds__(1024) void k_transpose(
    const float* __restrict__ x, float* __restrict__ xT) {
  int b = blockIdx.x >> 4, c = blockIdx.x & 15;
  __shared__ __align__(16) float xsT[II][NN + 4];   // +4: f4-aligned padded rows
  int tid = threadIdx.x;
  {
    int n = tid >> 3, i4 = (tid & 7) * 4;
    float4 v = *(const float4*)(x + (((size_t)(b * NN + n)) * CC + c) * II + i4);
    xsT[i4 + 0][n] = v.x; xsT[i4 + 1][n] = v.y;
    xsT[i4 + 2][n] = v.z; xsT[i4 + 3][n] = v.w;
  }
  __syncthreads();
  {
    int i = tid >> 5, n4 = tid & 31;
    float4 v = *(const float4*)(&xsT[i][n4 * 4]);   // row stride 528 B, 16B-aligned
    ((float4*)(xT + ((size_t)(b * CC + c)) * II * NN))[tid] = v;
  }
}

// 16-slot reduce-scatter across lane bits 1..4 (n4 bits); returns the
// fully-reduced value for slot qf = this lane's bit-pattern.
__device__ __forceinline__ float rs16(float p[16], int l) {
  bool u2 = (l >> 1) & 1, u4 = (l >> 2) & 1, u8 = (l >> 3) & 1, u16 = (l >> 4) & 1;
  #pragma unroll
  for (int k = 0; k < 8; ++k) {
    float s0 = u2 ? p[k] : p[k + 8];
    float r0 = __shfl_xor(s0, 2);
    p[k] = (u2 ? p[k + 8] : p[k]) + r0;
  }
  #pragma unroll
  for (int k = 0; k < 4; ++k) {
    float s0 = u4 ? p[k] : p[k + 4];
    float r0 = __shfl_xor(s0, 4);
    p[k] = (u4 ? p[k + 4] : p[k]) + r0;
  }
  #pragma unroll
  for (int k = 0; k < 2; ++k) {
    float s0 = u8 ? p[k] : p[k + 2];
    float r0 = __shfl_xor(s0, 8);
    p[k] = (u8 ? p[k + 2] : p[k]) + r0;
  }
  {
    float s0 = u16 ? p[0] : p[1];
    float r0 = __shfl_xor(s0, 16);
    p[0] = (u16 ? p[1] : p[0]) + r0;
  }
  p[0] += __shfl_xor(p[0], 32);          // allreduce the last n4 bit
  return p[0];
}

// ---- the whole routing loop. Block per (b, o-pair). 1024 threads. ----
__global__ __launch_bounds__(1024, 4) void k_route(
    const float* __restrict__ xT, const float* __restrict__ W,
    float* __restrict__ out) {
  int bid = blockIdx.x;
  int b = bid & 31, o0 = (bid >> 5) * 2;      // o-pair {o0, o0+1}
  int tid = threadIdx.x;

  __shared__ float Ws[CC * 2 * II * WP];            // 132 KB: W slice, padded
  __shared__ __align__(16) float bijL[2][CC][NN];   // 16 KB routing logits
  __shared__ float cw[2][CC][II];                   // 4 KB: cxs in C/A, wv in Wv/U
  __shared__ float partA[2][CC][JJ];                // 4 KB
  __shared__ float vs[2][JJ];
  __shared__ float redM[CC][2], redE[CC][2];
  __shared__ float smx[2], srin[2];
  // total ~160.3 KB -> 1 block/CU

  // ---- stage W slice into LDS (once; W is iteration-invariant) ----
  {
    int q = tid & 7, r0 = tid >> 3;
    #pragma unroll
    for (int k = 0; k < 8; ++k) {
      int rowid = r0 + k * 128;                   // rowid = (c<<6)|(o<<5)|i
      int c = rowid >> 6, o = (rowid >> 5) & 1, i = rowid & 31;
      float4 v = *(const float4*)(W + ((((size_t)c * OO + o0 + o) * II + i) * JJ) + q * 4);
      float* dst = &Ws[rowid * WP + q * 4];       // coalesced 1KB/instr reads
      dst[0] = v.x; dst[1] = v.y; dst[2] = v.z; dst[3] = v.w;
    }
  }

  // x -> registers (once): thread (c, n4, s) owns i=s*16..s*16+15, n=n4*4..+3
  int l = tid & 63;
  int c = tid >> 6, n4 = l >> 1, s = l & 1;
  const float4* xTb = (const float4*)(xT + (size_t)b * CC * II * NN);
  const float4* xp  = xTb + c * (II * NN / 4) + (s * 16) * (NN / 4) + n4;
  float4 xv[16];
  #pragma unroll
  for (int q = 0; q < 16; ++q) xv[q] = xp[q * (NN / 4)];  // 512B runs, coalesced

  {  // init: bijL = 0; smx=0, srin=1/MM makes iter-0 coef exactly uniform
    int o = tid >> 9, ci = (tid >> 5) & 15, m4i = tid & 31;
    *(float4*)(&bijL[o][ci][m4i * 4]) = make_float4(0.f, 0.f, 0.f, 0.f);
    if (tid < 2) { smx[tid] = 0.f; srin[tid] = 1.0f / (float)MM; }
  }
  __syncthreads();

  for (int it = 0; it < 3; ++it) {
    // --- C: cw[o][c][i] = sum_n coef(o,c,n)*x(c,n,i); coef recomputed
    //     from bijL (o's sequential to bound register pressure) ---
    {
      int qf = ((l >> 1) & 1) * 8 + ((l >> 2) & 1) * 4
             + ((l >> 3) & 1) * 2 + ((l >> 4) & 1);
      #pragma unroll
      for (int o = 0; o < 2; ++o) {
        float4 bb = *(const float4*)(&bijL[o][c][n4 * 4]);
        float m = smx[o], ri = srin[o];
        float cfx = __expf(bb.x - m) * ri, cfy = __expf(bb.y - m) * ri;
        float cfz = __expf(bb.z - m) * ri, cfw = __expf(bb.w - m) * ri;
        float p[16];
        #pragma unroll
        for (int q = 0; q < 16; ++q)
          p[q] = xv[q].x*cfx + xv[q].y*cfy + xv[q].z*cfz + xv[q].w*cfw;
        float r = rs16(p, l);
        if ((l & 32) == 0) cw[o][c][s * 16 + qf] = r;
      }
    }
    __syncthreads();

    // --- A: partA[o][c][j] = sum_i cw[o][c][i] * Ws[c,o,i,j]  (pure LDS) ---
    {
      int o = tid >> 9, cA = (tid >> 5) & 15, j = tid & 31;
      const float* wsp = &Ws[((cA * 2 + o) * II) * WP + j];
      float acc = 0.f;
      #pragma unroll 8
      for (int i = 0; i < II; ++i)
        acc += cw[o][cA][i] * wsp[i * WP];   // cw broadcast, Ws conflict-free
      partA[o][cA][j] = acc;
    }
    __syncthreads();

    // --- A-reduce + squash (final iter writes output) ---
    if (tid < 64) {
      int o = tid >> 5, j = tid & 31;
      float sA = 0.f;
      #pragma unroll
      for (int cR = 0; cR < CC; ++cR) sA += partA[o][cR][j];
      float msq = sA * sA;
      #pragma unroll
      for (int off = 16; off > 0; off >>= 1) msq += __shfl_xor(msq, off);
      float mag = sqrtf(msq) + EPS_;
      float a   = msq / (1.0f + msq);
      float vvq = a * sA / mag;
      if (it == 2) {
        int row = b * OO + (o0 + o);
        out[(size_t)row * JJ + j] = vvq;               // v_j: [B,1,O,J] flat
        if (j == 0) out[BB * OO * JJ + row] = a;       // a_j: [B,1,O,1] flat
      } else {
        vs[o][j] = vvq;
      }
    }
    if (it == 2) break;                   // uniform exit
    __syncthreads();

    // --- Wv: cw[o][c][i] = sum_j Ws[c,o,i,j] * vs[o][j]  (pure LDS) ---
    {
      int o = tid >> 9, cW = (tid >> 5) & 15, i = tid & 31;
      const float* wsr = &Ws[((cW * 2 + o) * II + i) * WP];
      float acc = 0.f;
      #pragma unroll 8
      for (int j = 0; j < JJ; ++j)
        acc += wsr[j] * vs[o][j];          // banks (i+j)%32: conflict-free
      cw[o][cW][i] = acc;                  // buffer now holds wv
    }
    __syncthreads();

    // --- U: bijL += x.wv (x from regs); stats + smx/srin for next C ---
    {
      float4 ac0 = make_float4(0.f,0.f,0.f,0.f);
      float4 ac1 = make_float4(0.f,0.f,0.f,0.f);
      #pragma unroll
      for (int q = 0; q < 16; ++q) {
        int i = s * 16 + q;
        float w0 = cw[0][c][i], w1 = cw[1][c][i];   // 2-addr broadcasts
        ac0.x += xv[q].x * w0; ac0.y += xv[q].y * w0;
        ac0.z += xv[q].z * w0; ac0.w += xv[q].w * w0;
        ac1.x += xv[q].x * w1; ac1.y += xv[q].y * w1;
        ac1.z += xv[q].z * w1; ac1.w += xv[q].w * w1;
      }
      // combine i-halves across the s-pair
      ac0.x += __shfl_xor(ac0.x, 1); ac0.y += __shfl_xor(ac0.y, 1);
      ac0.z += __shfl_xor(ac0.z, 1); ac0.w += __shfl_xor(ac0.w, 1);
      ac1.x += __shfl_xor(ac1.x, 1); ac1.y += __shfl_xor(ac1.y, 1);
      ac1.z += __shfl_xor(ac1.z, 1); ac1.w += __shfl_xor(ac1.w, 1);
      float4 r = (s == 0) ? ac0 : ac1;              // lane s owns o=s
      float4 bb = *(const float4*)(&bijL[s][c][n4 * 4]);
      r.x += bb.x; r.y += bb.y; r.z += bb.z; r.w += bb.w;
      *(float4*)(&bijL[s][c][n4 * 4]) = r;

      // per-wave max partials (parity-preserving: offsets 2..32)
      float m4 = fmaxf(fmaxf(r.x, r.y), fmaxf(r.z, r.w));
      #pragma unroll
      for (int off = 2; off <= 32; off <<= 1) m4 = fmaxf(m4, __shfl_xor(m4, off));
      int wave = tid >> 6;
      if ((tid & 63) <= 1) redM[wave][s] = m4;      // lane 0: o=0, lane 1: o=1
      __syncthreads();
      float mo = redM[0][s];                        // every thread reduces locally
      #pragma unroll
      for (int w2 = 1; w2 < CC; ++w2) mo = fmaxf(mo, redM[w2][s]);
      float ex = __expf(r.x - mo), ey = __expf(r.y - mo),
            ez = __expf(r.z - mo), ew = __expf(r.w - mo);
      float e = ex + ey + ez + ew;
      #pragma unroll
      for (int off = 2; off <= 32; off <<= 1) e += __shfl_xor(e, off);
      if ((tid & 63) <= 1) redE[wave][s] = e;
      __syncthreads();
      if (tid < 2) {                                // stats for next C
        float ss = 0.f, mm = redM[0][tid];
        #pragma unroll
        for (int w2 = 0; w2 < CC; ++w2) ss += redE[w2][tid];
        #pragma unroll
        for (int w2 = 1; w2 < CC; ++w2) mm = fmaxf(mm, redM[w2][tid]);
        smx[tid]  = mm;
        srin[tid] = 1.0f / ss;
      }
    }
    __syncthreads();
  }
}

extern "C" void kernel_launch(void* const* d_in, const int* in_sizes, int n_in,
                              void* d_out, int out_size, void* d_ws, size_t ws_size,
                              hipStream_t stream) {
  const float* x = (const float*)d_in[0];   // [B,N,C,I]
  const float* W = (const float*)d_in[1];   // [C,O,I,J]
  (void)in_sizes; (void)n_in;               // d_in[2] = number_of_nodes (fixed 128)
  float* out = (float*)d_out; (void)out_size;

  float* xT = (float*)d_ws;                 // 2,097,152 floats (8 MB), i-major
  (void)ws_size;

  k_transpose<<<BB * CC, 1024, 0, stream>>>(x, xT);
  k_route<<<BB * (OO / 2), 1024, 0, stream>>>(xT, W, out);
}